// Round 3
// baseline (164.544 us; speedup 1.0000x reference)
//
#include <hip/hip_runtime.h>

#define NHW 9216   // 96*96
#define NB 2
#define NCHUNK 16  // col chunks for k_simtop

typedef short s8v __attribute__((ext_vector_type(8)));       // 8x16-bit in 4 VGPRs
typedef _Float16 h8v __attribute__((ext_vector_type(8)));    // 8 f16
typedef float f4v __attribute__((ext_vector_type(4)));
typedef int i4v __attribute__((ext_vector_type(4)));         // 16 i8 / 4 i32
typedef unsigned int u32;
typedef unsigned short u16;

#define QSCALE 181.0f   // 127/0.7 — |rf elem| > 0.7 has ~0 probability for unit rows
#define IBIAS  2097152  // 2^21 > max |int sim| = 128*127*127 = 2,064,512

__device__ inline u16 f2h(float x) {
    _Float16 h = (_Float16)x;
    return *(u16*)&h;
}

// LDS-only barrier: waits ds ops, leaves global loads IN FLIGHT across the
// barrier (a plain __syncthreads would drain vmcnt(0) and kill the prefetch).
__device__ inline void lds_barrier() {
    asm volatile("s_waitcnt lgkmcnt(0)" ::: "memory");
    __builtin_amdgcn_s_barrier();
    __builtin_amdgcn_sched_barrier(0);
}

// counted-wait barrier for global_load_lds staging (k_simtop)
__device__ inline void wait_barrier() {
    asm volatile("s_waitcnt vmcnt(0)" ::: "memory");
    __builtin_amdgcn_s_barrier();
    __builtin_amdgcn_sched_barrier(0);
}

// ---------------------------------------------------------------------------
// K1: conv1 hh[g][256] = relu(X @ (W1hi+W1lo)^T + b1), 2-term f16 MFMA.
// R15: consumes X fp32 DIRECTLY (xsplit kernel deleted; 28 MB HBM round-trip
// of the xh intermediate eliminated). X tile transposed through LDS during
// staging (reg-stage: global f32 -> cvt f16 -> ds_write_b128 to [px][k]).
// W1 converted to hi/lo per K-tile from fp32 (L2-resident re-reads).
// Next-tile global loads issued after barrier2 -> in flight across both
// lgkmcnt-only barriers, covered by the MFMA phase.
// ---------------------------------------------------------------------------
__global__ __launch_bounds__(256, 2) void k_gemm1(const float* __restrict__ X,
                                                  const float* __restrict__ W1,
                                                  const float* __restrict__ b1,
                                                  u16* __restrict__ hh)
{
    union __align__(16) SM {
        struct { u16 Xs[128][72]; u16 Ws[16][512]; } stg;  // 18.4 + 16 KB
        u16 bounce[128 * 66];                              // epilogue transpose
    };
    __shared__ SM sm;
    const int tid = threadIdx.x;
    const int wave = tid >> 6, l = tid & 63, l15 = l & 15, q = l >> 4;
    const int bx = blockIdx.x;
    const int xcd = bx & 7, k = bx >> 3;
    const int pg = xcd * 18 + (k >> 2);          // px-group 0..143 (XCD-swizzled)
    const int c0 = (k & 3) * 64;
    const int bb = pg >= 72 ? 1 : 0;             // batch index
    const int hw0 = (pg - bb * 72) * 128;
    const int g0 = pg * 128;                     // global row base for hh
    const size_t xbase = (size_t)bb * 384 * NHW + hw0;

    // staging geometry: X 64k x 128px per tile; thread owns 8k x 4px
    const int xk8 = tid & 7;            // k-octet index
    const int xpx = (tid >> 3) * 4;     // first of 4 px

    f4v xl[8];      // 32 f32 X elems in flight
    f4v wl[2][2];   // 16 f32 W1 elems in flight

    auto do_load = [&](int kt) {
#pragma unroll
        for (int kr = 0; kr < 8; ++kr)
            xl[kr] = *(const f4v*)&X[xbase + (size_t)(kt + xk8 * 8 + kr) * NHW + xpx];
#pragma unroll
        for (int i = 0; i < 2; ++i) {
            int p = tid * 2 + i;
            int co = p & 63, ko = p >> 6;
            const float* src = &W1[(size_t)(c0 + co) * 384 + kt + ko * 8];
            wl[i][0] = *(const f4v*)&src[0];
            wl[i][1] = *(const f4v*)&src[4];
        }
    };

    auto do_write = [&]() {
        // X: transpose-through-LDS -> Xs[px][k] (rows padded to 72 u16)
#pragma unroll
        for (int j = 0; j < 4; ++j) {
            u16 hv[8];
#pragma unroll
            for (int kr = 0; kr < 8; ++kr) hv[kr] = f2h(xl[kr][j]);
            *(s8v*)&sm.stg.Xs[xpx + j][xk8 * 8] = *(s8v*)hv;
        }
        // W1: split fp32 -> hi/lo f16, layout matches MFMA B-frag reads
#pragma unroll
        for (int i = 0; i < 2; ++i) {
            int p = tid * 2 + i;
            int co = p & 63, ko = p >> 6;
            int cs = co >> 4, lc = co & 15, kf = ko >> 2, qk = ko & 3;
            u16 hi[8], lo[8];
#pragma unroll
            for (int e = 0; e < 8; ++e) {
                float v = wl[i][e >> 2][e & 3];
                _Float16 h = (_Float16)v;
                hi[e] = *(u16*)&h;
                lo[e] = f2h(v - (float)h);
            }
            *(s8v*)&sm.stg.Ws[kf * 4 + cs][(qk * 16 + lc) * 8] = *(s8v*)hi;
            *(s8v*)&sm.stg.Ws[8 + kf * 4 + cs][(qk * 16 + lc) * 8] = *(s8v*)lo;
        }
    };

    f4v acc[2][4];
#pragma unroll
    for (int s = 0; s < 2; ++s)
#pragma unroll
        for (int c = 0; c < 4; ++c) acc[s][c] = (f4v){0.f, 0.f, 0.f, 0.f};

    do_load(0);
    for (int t = 0; t < 6; ++t) {
        lds_barrier();                 // WAR: all waves' ds_reads of prev tile done
        do_write();                    // compiler waits vmcnt for xl/wl deps
        lds_barrier();                 // writes visible
        if (t < 5) do_load((t + 1) * 64);   // in flight across MFMA + barriers
        s8v ah[2][2];
#pragma unroll
        for (int s = 0; s < 2; ++s)
#pragma unroll
            for (int kf = 0; kf < 2; ++kf)
                ah[s][kf] = *(const s8v*)&sm.stg.Xs[wave * 32 + s * 16 + l15][kf * 32 + q * 8];
#pragma unroll
        for (int kf = 0; kf < 2; ++kf)
#pragma unroll
            for (int cs = 0; cs < 4; ++cs) {
                s8v bh = *(const s8v*)&sm.stg.Ws[kf * 4 + cs][l * 8];
                s8v bl = *(const s8v*)&sm.stg.Ws[8 + kf * 4 + cs][l * 8];
#pragma unroll
                for (int s = 0; s < 2; ++s) {
                    acc[s][cs] = __builtin_amdgcn_mfma_f32_16x16x32_f16(*(h8v*)&ah[s][kf], *(h8v*)&bh, acc[s][cs], 0, 0, 0);
                    acc[s][cs] = __builtin_amdgcn_mfma_f32_16x16x32_f16(*(h8v*)&ah[s][kf], *(h8v*)&bl, acc[s][cs], 0, 0, 0);
                }
            }
    }
    __syncthreads();   // all waves done with stg before bounce overwrites (union)

#pragma unroll
    for (int s = 0; s < 2; ++s)
#pragma unroll
        for (int cs = 0; cs < 4; ++cs) {
            int c = cs * 16 + l15;
            float bv = b1[c0 + c];
#pragma unroll
            for (int r = 0; r < 4; ++r) {
                int px = wave * 32 + s * 16 + q * 4 + r;
                sm.bounce[px * 66 + c] = f2h(fmaxf(acc[s][cs][r] + bv, 0.f));
            }
        }
    __syncthreads();
    {
        int px = tid >> 1, half = tid & 1;
        u32 tmp[16];
#pragma unroll
        for (int j = 0; j < 16; ++j)
            tmp[j] = *(const u32*)&sm.bounce[px * 66 + half * 32 + j * 2];
        size_t o = (size_t)(g0 + px) * 256 + c0 + half * 32;
#pragma unroll
        for (int j = 0; j < 4; ++j)
            *(s8v*)&hh[o + j * 8] = ((s8v*)tmp)[j];
    }
}

// ---------------------------------------------------------------------------
// K2: FUSED conv2 + L2-normalize. 64 px x 128 couts. R15: W2 read as fp32 and
// converted to f16 into LDS at block start (one-time, L2-resident) — the w2h
// intermediate and the weight-split producer are gone.
// ---------------------------------------------------------------------------
__global__ __launch_bounds__(256) void k_gemm2n(const u16* __restrict__ hh,
                                                const float* __restrict__ W2,
                                                const float* __restrict__ b2,
                                                float* __restrict__ rf,
                                                signed char* __restrict__ qi8)
{
    __shared__ u16 Bs[64][512];   // 64 KB: cid = kf*8 + cst
    const int tid = threadIdx.x;
    const int wave = tid >> 6, l = tid & 63, l15 = l & 15, q = l >> 4;
    const int bx = blockIdx.x;
    const int xcd = bx & 7, k = bx >> 3;
    const int g0 = (xcd * 36 + k) * 64;

    // one-time W2 fp32 -> f16 conversion into LDS (4096 b128 tiles of 8 k)
#pragma unroll
    for (int i = 0; i < 16; ++i) {
        int p = i * 256 + tid;
        int c = p & 127, k8g = p >> 7;
        const float* src = &W2[(size_t)c * 256 + k8g * 8];
        f4v a0 = *(const f4v*)&src[0];
        f4v a1 = *(const f4v*)&src[4];
        u16 hv[8];
#pragma unroll
        for (int e = 0; e < 4; ++e) { hv[e] = f2h(a0[e]); hv[4 + e] = f2h(a1[e]); }
        int cst = c >> 4, lc = c & 15, kf = k8g >> 2, qk = k8g & 3;
        *(s8v*)&Bs[kf * 8 + cst][(qk * 16 + lc) * 8] = *(s8v*)hv;
    }
    __syncthreads();

    const int gw = g0 + wave * 16;
    f4v acc[8];
#pragma unroll
    for (int c = 0; c < 8; ++c) acc[c] = (f4v){0.f, 0.f, 0.f, 0.f};

#pragma unroll
    for (int kf = 0; kf < 8; ++kf) {
        s8v ah = *(const s8v*)&hh[(size_t)(gw + l15) * 256 + kf * 32 + q * 8];
#pragma unroll
        for (int cst = 0; cst < 8; ++cst) {
            s8v bh = *(const s8v*)&Bs[kf * 8 + cst][l * 8];
            acc[cst] = __builtin_amdgcn_mfma_f32_16x16x32_f16(*(h8v*)&ah, *(h8v*)&bh, acc[cst], 0, 0, 0);
        }
    }

    float ssq[4] = {0.f, 0.f, 0.f, 0.f};
#pragma unroll
    for (int cst = 0; cst < 8; ++cst) {
        float bv = b2[cst * 16 + l15];
#pragma unroll
        for (int r = 0; r < 4; ++r) {
            acc[cst][r] += bv;
            ssq[r] += acc[cst][r] * acc[cst][r];
        }
    }
#pragma unroll
    for (int r = 0; r < 4; ++r) {
        ssq[r] += __shfl_xor(ssq[r], 1, 64);
        ssq[r] += __shfl_xor(ssq[r], 2, 64);
        ssq[r] += __shfl_xor(ssq[r], 4, 64);
        ssq[r] += __shfl_xor(ssq[r], 8, 64);
        ssq[r] = 1.0f / fmaxf(sqrtf(ssq[r]), 1e-12f);
    }
#pragma unroll
    for (int cst = 0; cst < 8; ++cst)
#pragma unroll
        for (int r = 0; r < 4; ++r) {
            float val = acc[cst][r] * ssq[r];
            size_t o = (size_t)(gw + q * 4 + r) * 128 + cst * 16 + l15;
            rf[o] = val;
            int qv = __float2int_rn(fminf(fmaxf(val * QSCALE, -127.f), 127.f));
            qi8[o] = (signed char)qv;
        }
}

// ---------------------------------------------------------------------------
// K3: sim selection via i8 MFMA (16x16x64) + int sortable keys (counted-wait).
// ---------------------------------------------------------------------------
__global__ __launch_bounds__(256, 4) void k_simtop(const signed char* __restrict__ qi,
                                                   int* __restrict__ cidx)
{
    __shared__ signed char Bs[2][8][1024];   // 16 KB double buffer
    const int tid  = threadIdx.x;
    const int wave = tid >> 6, l = tid & 63, l15 = l & 15, q = l >> 4;
    const int b     = blockIdx.z;
    const int rbase = blockIdx.x * 128;
    const int chunk = blockIdx.y;
    const int cbase = chunk * 576;
    const size_t base = (size_t)b * NHW;
    const int wr0 = rbase + wave * 32;

    i4v ah[2][2];
#pragma unroll
    for (int s = 0; s < 2; ++s) {
        int row = wr0 + s * 16 + l15;
#pragma unroll
        for (int kf = 0; kf < 2; ++kf)
            ah[s][kf] = *(const i4v*)&qi[(base + row) * 128 + kf * 64 + q * 16];
    }

    auto stage = [&](int colt, int buf) {
#pragma unroll
        for (int r = 0; r < 2; ++r) {
            int cid = r * 4 + wave;                 // cid = kf*4 + cs
            int kf = cid >> 2, cs = cid & 3;
            int col = colt + cs * 16 + l15;
            const signed char* src = qi + (base + col) * 128 + kf * 64 + q * 16;
            __builtin_amdgcn_global_load_lds(
                (const __attribute__((address_space(1))) void*)src,
                (__attribute__((address_space(3))) void*)&Bs[buf][cid][0],
                16, 0, 0);
        }
    };

    u32 bk[2][4];
#pragma unroll
    for (int s = 0; s < 2; ++s)
#pragma unroll
        for (int r = 0; r < 4; ++r) bk[s][r] = 0u;

    stage(cbase, 0);

    for (int ct = 0; ct < 9; ++ct) {
        const int colt = cbase + ct * 64;
        const int buf  = ct & 1;
        wait_barrier();                       // buf staged; WAR-safe for buf^1
        if (ct < 8) stage(colt + 64, buf ^ 1);

        i4v acc[2][4];
#pragma unroll
        for (int s = 0; s < 2; ++s)
#pragma unroll
            for (int c = 0; c < 4; ++c) acc[s][c] = (i4v){IBIAS, IBIAS, IBIAS, IBIAS};

#pragma unroll
        for (int kf = 0; kf < 2; ++kf)
#pragma unroll
            for (int cs = 0; cs < 4; ++cs) {
                i4v bh = *(const i4v*)&Bs[buf][kf * 4 + cs][l * 16];
#pragma unroll
                for (int s = 0; s < 2; ++s)
                    acc[s][cs] = __builtin_amdgcn_mfma_i32_16x16x64_i8(ah[s][kf], bh, acc[s][cs], 0, 0, 0);
            }

        const u32 tagv = (u32)(ct << 2);
        const bool hasdiag = (colt < wr0 + 32) && (wr0 < colt + 64);
        if (hasdiag) {
#pragma unroll
            for (int s = 0; s < 2; ++s)
#pragma unroll
                for (int r = 0; r < 4; ++r) {
                    const int rr = wr0 + s * 16 + q * 4 + r;
                    u32 km = 0u;
#pragma unroll
                    for (int cs = 0; cs < 4; ++cs) {
                        u32 kk = ((u32)acc[s][cs][r] << 6) | (tagv | (u32)cs);
                        if (colt + cs * 16 + l15 == rr) kk = 0u;
                        km = kk > km ? kk : km;
                    }
                    bk[s][r] = km > bk[s][r] ? km : bk[s][r];
                }
        } else {
#pragma unroll
            for (int s = 0; s < 2; ++s)
#pragma unroll
                for (int r = 0; r < 4; ++r) {
                    u32 km = 0u;
#pragma unroll
                    for (int cs = 0; cs < 4; ++cs) {
                        u32 kk = ((u32)acc[s][cs][r] << 6) | (tagv | (u32)cs);
                        km = kk > km ? kk : km;
                    }
                    bk[s][r] = km > bk[s][r] ? km : bk[s][r];
                }
        }
    }

    // decode keys, merge (sim,col) across 16 lanes per row; write chunk winner
#pragma unroll
    for (int s = 0; s < 2; ++s)
#pragma unroll
        for (int r = 0; r < 4; ++r) {
            u32 key = bk[s][r];
            int sv = (int)(key >> 6);            // biased int sim
            int ctw = (int)((key >> 2) & 15u);
            int csw = (int)(key & 3u);
            int col = cbase + ctw * 64 + csw * 16 + l15;
#pragma unroll
            for (int d = 1; d < 16; d <<= 1) {
                int ov = __shfl_xor(sv, d, 64);
                int oi = __shfl_xor(col, d, 64);
                bool p = (ov > sv) || (ov == sv && oi < col);
                sv  = p ? ov : sv;
                col = p ? oi : col;
            }
            if (l15 == 0) {
                int row = wr0 + s * 16 + q * 4 + r;
                cidx[(base + row) * NCHUNK + chunk] = col;
            }
        }
}

// ---------------------------------------------------------------------------
// K4: exact fp32 re-rank of 16 candidates + distance + mask
// ---------------------------------------------------------------------------
__global__ __launch_bounds__(256) void k_finish(const float* __restrict__ rf,
                                                const int* __restrict__ cidx,
                                                float* __restrict__ out)
{
    const int tid = threadIdx.x;
    const int g = blockIdx.x * 16 + (tid >> 4);
    const int l15 = tid & 15;
    const int b = g / NHW;
    const size_t rowbase = (size_t)b * NHW;

    const float* x = rf + (size_t)g * 128;
    f4v x0 = *(const f4v*)&x[l15 * 8];
    f4v x1 = *(const f4v*)&x[l15 * 8 + 4];

    float bestS = -2.f; int bestI = 0;
#pragma unroll
    for (int j = 0; j < NCHUNK; ++j) {
        int c = cidx[(size_t)g * NCHUNK + j];
        const float* y = rf + (rowbase + c) * 128;
        f4v y0 = *(const f4v*)&y[l15 * 8];
        f4v y1 = *(const f4v*)&y[l15 * 8 + 4];
        float s = x0[0]*y0[0] + x0[1]*y0[1] + x0[2]*y0[2] + x0[3]*y0[3]
                + x1[0]*y1[0] + x1[1]*y1[1] + x1[2]*y1[2] + x1[3]*y1[3];
#pragma unroll
        for (int d = 1; d < 16; d <<= 1) s += __shfl_xor(s, d, 64);
        bool p = (s > bestS) || (s == bestS && c < bestI);
        bestS = p ? s : bestS;
        bestI = p ? c : bestI;
    }

    const float* y = rf + (rowbase + bestI) * 128;
    f4v y0 = *(const f4v*)&y[l15 * 8];
    f4v y1 = *(const f4v*)&y[l15 * 8 + 4];
    float d0 = x0[0]-y0[0], d1 = x0[1]-y0[1], d2 = x0[2]-y0[2], d3 = x0[3]-y0[3];
    float e0 = x1[0]-y1[0], e1 = x1[1]-y1[1], e2 = x1[2]-y1[2], e3 = x1[3]-y1[3];
    float ss = d0*d0 + d1*d1 + d2*d2 + d3*d3 + e0*e0 + e1*e1 + e2*e2 + e3*e3;
#pragma unroll
    for (int d = 1; d < 16; d <<= 1) ss += __shfl_xor(ss, d, 64);
    if (l15 == 0) {
        float dist = sqrtf(ss);
        out[NB * NHW + g] = dist;
        out[g] = dist > 0.2f ? 1.0f : 0.0f;
    }
}

// ===========================================================================
extern "C" void kernel_launch(void* const* d_in, const int* in_sizes, int n_in,
                              void* d_out, int out_size, void* d_ws, size_t ws_size,
                              hipStream_t stream) {
    const float* features = (const float*)d_in[0];
    const float* W1 = (const float*)d_in[1];
    const float* b1 = (const float*)d_in[2];
    const float* W2 = (const float*)d_in[3];
    const float* b2 = (const float*)d_in[4];
    float* out = (float*)d_out;
    float* ws  = (float*)d_ws;

    // ws layout (float offsets), peak 5,603,328 f = 22.4 MB (xh/w1h/w1l/w2h gone):
    //   rf   [0,       2359296)  fp32 18432x128
    //   qi8  [2359296, 2949120)  int8 18432x128
    //   hh   [2949120, 5308416)  f16  18432x256
    //   cidx [5308416, 5603328)  int  18432x16
    float* rf   = ws;
    signed char* qi8 = (signed char*)(ws + 2359296);
    u16*   hh   = (u16*)(ws + 2949120);
    int*   cidx = (int*)(ws + 5308416);

    // conv1 straight from X fp32 (transpose-in-LDS staging; W1 hi/lo in-kernel)
    k_gemm1<<<576, 256, 0, stream>>>(features, W1, b1, hh);
    // fused conv2 + normalize + i8 quantize (W2 f16-converted in-kernel)
    k_gemm2n<<<288, 256, 0, stream>>>(hh, W2, b2, rf, qi8);
    // i8 sim selection: per-chunk argmax candidates
    k_simtop<<<dim3(72, NCHUNK, NB), 256, 0, stream>>>(qi8, cidx);
    // exact fp32 re-rank of 16 candidates + distance + mask
    k_finish<<<1152, 256, 0, stream>>>(rf, cidx, out);
}